// Round 8
// baseline (53871.948 us; speedup 1.0000x reference)
//
#include <hip/hip_runtime.h>
#include <cstddef>

// Problem constants
#define NV   30
#define NDH  512
#define NE   256
#define NKV  128
#define NB   256
#define NT   800
#define NL   300
#define NKX  896   // E + KV + DH

#define PRED_SIZE (NB*NL*NV)   // predictions; attn_plot (NL*NT) follows

typedef float v4f __attribute__((ext_vector_type(4)));
typedef short bf16x8 __attribute__((ext_vector_type(8)));
typedef unsigned short ushort_t;

// ---- workspace float offsets (FIXED: XEC is 2 planes = 98304 floats) ----
#define OFF_C1   0                      // C1[512][256]                     (131072 f)
#define OFF_C2   131072                 // C2[128][256]                     (32768 f)
#define OFF_H2F  163840                 // H2f[256][128]                    (32768 f)
#define OFF_XEC  196608                 // XEC ushort[2 pl][256 b][384]     (98304 f)
#define OFF_XH1  294912                 // XH1 ushort[2 par][2 pl][256][512](262144 f)
#define OFF_XH2  557056                 // XH2 ushort[2 par][2 pl][256][128](65536 f)
#define OFF_BAR  622592                 // barrier: cnt, gen, broken        (256 f pad)
#define OFF_WF   622848                 // Wf  ushort[2][128][28][64][8]    (1835008 f)
#define OFF_WF2  2457856                // Wf2 ushort[2][32][20][64][8]     (327680 f)
#define OFF_BS1  2785536                // bsum1[2048]
#define OFF_BS2  2787584                // bsum2[512]
// end 2788096 floats = 11.2 MB

#define WF_PL   ((size_t)128*28*64*8)
#define WF2_PL  ((size_t)32*20*64*8)

struct DecParams {
  const float* key; const float* val; const int* elen; const int* y;
  const float* emb;
  const float* wi1; const float* wh1; const float* bi1; const float* bh1;
  const float* wi2; const float* wh2; const float* bi2; const float* bh2;
  const float* ob;
  float* out; float* ws;
};

__device__ __forceinline__ float sigm(float x)  { return 1.0f/(1.0f + __expf(-x)); }
__device__ __forceinline__ float tanh_f(float x){ return 1.0f - 2.0f/(__expf(2.0f*x)+1.0f); }

__device__ __forceinline__ ushort_t bf16_rne(float x){
  union { float f; unsigned u; } v; v.f = x;
  unsigned r = v.u + 0x7FFFu + ((v.u >> 16) & 1u);
  return (ushort_t)(r >> 16);
}
__device__ __forceinline__ float bf16_to_f(ushort_t h){
  union { float f; unsigned u; } v; v.u = ((unsigned)h) << 16;
  return v.f;
}

// ---- grid barrier: sense-reversing, SYSTEM scope, fail-fast + diagnosable ----
__device__ __forceinline__ void gridbar(int* bar, int G)
{
  __syncthreads();
  if (threadIdx.x == 0) {
    __threadfence_system();   // release
    const int g = __hip_atomic_load(&bar[1], __ATOMIC_RELAXED, __HIP_MEMORY_SCOPE_SYSTEM);
    const int v = __hip_atomic_fetch_add(&bar[0], 1, __ATOMIC_ACQ_REL, __HIP_MEMORY_SCOPE_SYSTEM);
    if (v == G - 1) {
      __hip_atomic_store(&bar[0], 0, __ATOMIC_RELAXED, __HIP_MEMORY_SCOPE_SYSTEM);
      __hip_atomic_fetch_add(&bar[1], 1, __ATOMIC_ACQ_REL, __HIP_MEMORY_SCOPE_SYSTEM);
    } else {
      long spins = 0;
      while (__hip_atomic_load(&bar[1], __ATOMIC_ACQUIRE, __HIP_MEMORY_SCOPE_SYSTEM) == g) {
        __builtin_amdgcn_s_sleep(8);
        if (++spins > (1L << 20)) {
          __hip_atomic_store(&bar[2], 1, __ATOMIC_RELAXED, __HIP_MEMORY_SCOPE_SYSTEM);
          break;
        }
        if (__hip_atomic_load(&bar[2], __ATOMIC_RELAXED, __HIP_MEMORY_SCOPE_SYSTEM)) break;
      }
    }
    __threadfence_system();   // acquire
  }
  __syncthreads();
}

// ---------------- init: zero state + barrier region ----------------
__global__ void __launch_bounds__(256)
k_init(DecParams P)
{
  P.ws[blockIdx.x * 256 + threadIdx.x] = 0.0f;   // grid 2433 -> floats [0, 622848)
}

// ---------------- initX: XEC ctx rows <- value[:,0,:] ----------------
__global__ void __launch_bounds__(256)
k_initX(DecParams P)
{
  const int b = blockIdx.x, tid = threadIdx.x;
  if (tid < 128) {
    ushort_t* xec = (ushort_t*)(P.ws + OFF_XEC);
    const float v = P.val[(size_t)b*NT*NKV + tid];
    const ushort_t hi = bf16_rne(v);
    const ushort_t lo = bf16_rne(v - bf16_to_f(hi));
    xec[((size_t)0*256 + b)*384 + 256 + tid] = hi;
    xec[((size_t)1*256 + b)*384 + 256 + tid] = lo;
  }
}

// ---------------- initW: W1 -> split-bf16 fragment-linear Wf; bsum1 ----------------
__global__ void __launch_bounds__(256)
k_initW(DecParams P)
{
  const int r = blockIdx.x;            // 0..2047
  const int tid = threadIdx.x;
  ushort_t* wf = (ushort_t*)(P.ws + OFF_WF);
  const int rt = r >> 4;
#pragma unroll
  for (int i = 0; i < 4; ++i) {
    const int k = i*256 + tid;
    if (k < NKX) {
      const float w = (k < 384) ? P.wi1[(size_t)r*384 + k]
                                : P.wh1[(size_t)r*512 + (k - 384)];
      const ushort_t hi = bf16_rne(w);
      const ushort_t lo = bf16_rne(w - bf16_to_f(hi));
      const int kc = k >> 5;
      const int lane = (r & 15) | (((k >> 3) & 3) << 4);
      const int e = k & 7;
      const size_t base = ((((size_t)rt)*28 + kc)*64 + lane)*8 + e;
      wf[base] = hi;
      wf[WF_PL + base] = lo;
    }
  }
  if (tid == 0) P.ws[OFF_BS1 + r] = P.bi1[r] + P.bh1[r];
}

// ---------------- initW2 ----------------
__global__ void __launch_bounds__(256)
k_initW2(DecParams P)
{
  const int r = blockIdx.x;            // 0..511
  const int tid = threadIdx.x;
  ushort_t* wf = (ushort_t*)(P.ws + OFF_WF2);
  const int rt = r >> 4;
#pragma unroll
  for (int i = 0; i < 3; ++i) {
    const int k = i*256 + tid;
    if (k < 640) {
      const float w = (k < 512) ? P.wi2[(size_t)r*512 + k]
                                : P.wh2[(size_t)r*128 + (k - 512)];
      const ushort_t hi = bf16_rne(w);
      const ushort_t lo = bf16_rne(w - bf16_to_f(hi));
      const int kc = k >> 5;
      const int lane = (r & 15) | (((k >> 3) & 3) << 4);
      const int e = k & 7;
      const size_t base = ((((size_t)rt)*20 + kc)*64 + lane)*8 + e;
      wf[base] = hi;
      wf[WF2_PL + base] = lo;
    }
  }
  if (tid == 0) P.ws[OFF_BS2 + r] = P.bi2[r] + P.bh2[r];
}

// ---------------- persistent kernel: all 300 steps, grid = G resident blocks ----------------
union SMem {
  struct { ushort_t xs[2][32][136]; float gbuf[4][16][33]; } ab;   // 25.9 KB
  struct { float e[NT]; float qc[256]; float red[16]; float ctxp[16][132]; } c; // 12.7 KB
};

__global__ void __launch_bounds__(512)
k_persist(DecParams P, int G)
{
  __shared__ SMem sm;
  const int tid = threadIdx.x;
  const int bid = blockIdx.x;
  const int w = tid >> 6, lane = tid & 63;
  const int lr = lane & 15, lk8 = (lane >> 4) * 8;
  const int srow = tid >> 4, sk = (tid & 15) * 8;

  float* ws = P.ws;
  int* bar = (int*)(ws + OFF_BAR);
  const ushort_t* Wf  = (const ushort_t*)(ws + OFF_WF);
  const ushort_t* Wf2 = (const ushort_t*)(ws + OFF_WF2);
  ushort_t* XEC = (ushort_t*)(ws + OFF_XEC);
  ushort_t* XH1 = (ushort_t*)(ws + OFF_XH1);
  ushort_t* XH2 = (ushort_t*)(ws + OFF_XH2);
  float* C1  = ws + OFF_C1;
  float* C2  = ws + OFF_C2;
  float* H2f = ws + OFF_H2F;
  const float* BS1 = ws + OFF_BS1;
  const float* BS2 = ws + OFF_BS2;

#pragma unroll 1
  for (int t = 0; t < NL; ++t) {
    const int cur = t & 1, nxt = (t + 1) & 1;

    // ================= Phase A: LSTM1 (256 tiles) =================
#pragma unroll 1
    for (int tileA = bid; tileA < 256; tileA += G) {
      const int mt = tileA & 31, nt = tileA >> 5;
      const int b0 = nt * 32, j0 = mt * 16;
      const int g = w >> 1, ct = w & 1;
      const int rt16 = g*32 + mt;
      v4f acc = (v4f)0.0f;

#pragma unroll 1
      for (int p = 0; p < 7; ++p) {
        __syncthreads();
        {
          const ushort_t *s0, *s1;
          if (p < 3) {
            s0 = XEC + ((size_t)(0*256 + b0 + srow))*384 + p*128 + sk;
            s1 = XEC + ((size_t)(1*256 + b0 + srow))*384 + p*128 + sk;
          } else {
            s0 = XH1 + (((size_t)cur*2 + 0)*256 + b0 + srow)*512 + (p-3)*128 + sk;
            s1 = XH1 + (((size_t)cur*2 + 1)*256 + b0 + srow)*512 + (p-3)*128 + sk;
          }
          *(bf16x8*)&sm.ab.xs[0][srow][sk] = *(const bf16x8*)s0;
          *(bf16x8*)&sm.ab.xs[1][srow][sk] = *(const bf16x8*)s1;
        }
        __syncthreads();
#pragma unroll
        for (int kc2 = 0; kc2 < 4; ++kc2) {
          const int kcg = p*4 + kc2;
          bf16x8 ah = *(const bf16x8*)(Wf + (((size_t)rt16*28 + kcg)*64 + lane)*8);
          bf16x8 al = *(const bf16x8*)(Wf + WF_PL + (((size_t)rt16*28 + kcg)*64 + lane)*8);
          const int lk = kc2*32 + lk8;
          bf16x8 bh = *(const bf16x8*)&sm.ab.xs[0][ct*16 + lr][lk];
          bf16x8 bl = *(const bf16x8*)&sm.ab.xs[1][ct*16 + lr][lk];
          acc = __builtin_amdgcn_mfma_f32_16x16x32_bf16(ah, bh, acc, 0, 0, 0);
          acc = __builtin_amdgcn_mfma_f32_16x16x32_bf16(ah, bl, acc, 0, 0, 0);
          acc = __builtin_amdgcn_mfma_f32_16x16x32_bf16(al, bh, acc, 0, 0, 0);
        }
      }
      __syncthreads();
      {
        const int rg = (lane >> 4) * 4;
#pragma unroll
        for (int j = 0; j < 4; ++j) sm.ab.gbuf[g][rg + j][ct*16 + lr] = acc[j];
      }
      __syncthreads();
      {
        const int jj = tid >> 5, bq = tid & 31;
        const int jg = j0 + jj, b = b0 + bq;
        const float iv = sigm (sm.ab.gbuf[0][jj][bq] + BS1[       jg]);
        const float fv = sigm (sm.ab.gbuf[1][jj][bq] + BS1[ 512 + jg]);
        const float gv = tanh_f(sm.ab.gbuf[2][jj][bq] + BS1[1024 + jg]);
        const float ov = sigm (sm.ab.gbuf[3][jj][bq] + BS1[1536 + jg]);
        const float cn = fv * C1[(size_t)jg*256 + b] + iv * gv;
        C1[(size_t)jg*256 + b] = cn;
        const float h = ov * tanh_f(cn);
        const ushort_t hi = bf16_rne(h);
        const ushort_t lo = bf16_rne(h - bf16_to_f(hi));
        XH1[(((size_t)nxt*2 + 0)*256 + b)*512 + jg] = hi;
        XH1[(((size_t)nxt*2 + 1)*256 + b)*512 + jg] = lo;
      }
    }
    gridbar(bar, G);

    // ================= Phase B: LSTM2 (64 tiles) =================
#pragma unroll 1
    for (int tileB = bid; tileB < 64; tileB += G) {
      const int mt = tileB & 7, nt = tileB >> 3;
      const int b0 = nt * 32, j0 = mt * 16;
      const int g = w >> 1, ct = w & 1;
      const int rt16 = g*8 + mt;
      v4f acc = (v4f)0.0f;

#pragma unroll 1
      for (int p = 0; p < 5; ++p) {
        __syncthreads();
        {
          const ushort_t *s0, *s1;
          if (p < 4) {
            s0 = XH1 + (((size_t)nxt*2 + 0)*256 + b0 + srow)*512 + p*128 + sk;
            s1 = XH1 + (((size_t)nxt*2 + 1)*256 + b0 + srow)*512 + p*128 + sk;
          } else {
            s0 = XH2 + (((size_t)cur*2 + 0)*256 + b0 + srow)*128 + sk;
            s1 = XH2 + (((size_t)cur*2 + 1)*256 + b0 + srow)*128 + sk;
          }
          *(bf16x8*)&sm.ab.xs[0][srow][sk] = *(const bf16x8*)s0;
          *(bf16x8*)&sm.ab.xs[1][srow][sk] = *(const bf16x8*)s1;
        }
        __syncthreads();
#pragma unroll
        for (int kc2 = 0; kc2 < 4; ++kc2) {
          const int kcg = p*4 + kc2;
          bf16x8 ah = *(const bf16x8*)(Wf2 + (((size_t)rt16*20 + kcg)*64 + lane)*8);
          bf16x8 al = *(const bf16x8*)(Wf2 + WF2_PL + (((size_t)rt16*20 + kcg)*64 + lane)*8);
          const int lk = kc2*32 + lk8;
          bf16x8 bh = *(const bf16x8*)&sm.ab.xs[0][ct*16 + lr][lk];
          bf16x8 bl = *(const bf16x8*)&sm.ab.xs[1][ct*16 + lr][lk];
          acc = __builtin_amdgcn_mfma_f32_16x16x32_bf16(ah, bh, acc, 0, 0, 0);
          acc = __builtin_amdgcn_mfma_f32_16x16x32_bf16(ah, bl, acc, 0, 0, 0);
          acc = __builtin_amdgcn_mfma_f32_16x16x32_bf16(al, bh, acc, 0, 0, 0);
        }
      }
      __syncthreads();
      {
        const int rg = (lane >> 4) * 4;
#pragma unroll
        for (int j = 0; j < 4; ++j) sm.ab.gbuf[g][rg + j][ct*16 + lr] = acc[j];
      }
      __syncthreads();
      {
        const int jj = tid >> 5, bq = tid & 31;
        const int j2 = j0 + jj, b = b0 + bq;
        const float iv = sigm (sm.ab.gbuf[0][jj][bq] + BS2[      j2]);
        const float fv = sigm (sm.ab.gbuf[1][jj][bq] + BS2[128 + j2]);
        const float gv = tanh_f(sm.ab.gbuf[2][jj][bq] + BS2[256 + j2]);
        const float ov = sigm (sm.ab.gbuf[3][jj][bq] + BS2[384 + j2]);
        const float cn = fv * C2[(size_t)j2*256 + b] + iv * gv;
        C2[(size_t)j2*256 + b] = cn;
        const float h = ov * tanh_f(cn);
        H2f[(size_t)b*128 + j2] = h;
        const ushort_t hi = bf16_rne(h);
        const ushort_t lo = bf16_rne(h - bf16_to_f(hi));
        XH2[(((size_t)nxt*2 + 0)*256 + b)*128 + j2] = hi;
        XH2[(((size_t)nxt*2 + 1)*256 + b)*128 + j2] = lo;
      }
    }
    gridbar(bar, G);

    // ================= Phase C: attention + pred + x_next (256 tiles) =================
#pragma unroll 1
    for (int b = bid; b < NB; b += G) {
      __syncthreads();   // protect sm.c reuse across b-tiles
      const int len = P.elen[b];

      if (tid < 128) sm.c.qc[tid] = H2f[(size_t)b*128 + tid];
      __syncthreads();

      // energy
      const int lg = tid & 15, grp = tid >> 4;
      const v4f qa = *(const v4f*)&sm.c.qc[lg*8];
      const v4f qb = *(const v4f*)&sm.c.qc[lg*8 + 4];
      const v4f* kb = (const v4f*)(P.key + (size_t)b*NT*NKV);
#pragma unroll 1
      for (int s = 0; s < 13; ++s) {
        const int ta = s*64 + grp, tb = ta + 32;
        float pa = 0.0f, pb = 0.0f;
        if (ta < len) {
          v4f k0 = kb[(size_t)ta*32 + lg*2], k1 = kb[(size_t)ta*32 + lg*2 + 1];
          v4f d = k0*qa + k1*qb; pa = d[0]+d[1]+d[2]+d[3];
        }
        if (tb < len) {
          v4f k0 = kb[(size_t)tb*32 + lg*2], k1 = kb[(size_t)tb*32 + lg*2 + 1];
          v4f d = k0*qa + k1*qb; pb = d[0]+d[1]+d[2]+d[3];
        }
        pa += __shfl_xor(pa, 1); pb += __shfl_xor(pb, 1);
        pa += __shfl_xor(pa, 2); pb += __shfl_xor(pb, 2);
        pa += __shfl_xor(pa, 4); pb += __shfl_xor(pb, 4);
        pa += __shfl_xor(pa, 8); pb += __shfl_xor(pb, 8);
        if (lg == 0) {
          if (ta < len) sm.c.e[ta] = pa;
          if (tb < len) sm.c.e[tb] = pb;
        }
      }
      for (int tt = len + tid; tt < NT; tt += 512) sm.c.e[tt] = -1e9f;
      __syncthreads();

      // softmax
      const int wid = tid >> 6;
      const float x0 = sm.c.e[tid];
      const float x1 = (tid < NT - 512) ? sm.c.e[512 + tid] : -3.0e38f;
      float m = fmaxf(x0, x1);
      m = fmaxf(m, __shfl_xor(m, 1));  m = fmaxf(m, __shfl_xor(m, 2));
      m = fmaxf(m, __shfl_xor(m, 4));  m = fmaxf(m, __shfl_xor(m, 8));
      m = fmaxf(m, __shfl_xor(m, 16)); m = fmaxf(m, __shfl_xor(m, 32));
      if ((tid & 63) == 0) sm.c.red[wid] = m;
      __syncthreads();
      m = sm.c.red[0];
#pragma unroll
      for (int i = 1; i < 8; ++i) m = fmaxf(m, sm.c.red[i]);
      const float p0 = __expf(x0 - m);
      const float p1 = (tid < NT - 512) ? __expf(x1 - m) : 0.0f;
      float ssum = p0 + p1;
      ssum += __shfl_xor(ssum, 1);  ssum += __shfl_xor(ssum, 2);  ssum += __shfl_xor(ssum, 4);
      ssum += __shfl_xor(ssum, 8);  ssum += __shfl_xor(ssum, 16); ssum += __shfl_xor(ssum, 32);
      __syncthreads();
      if ((tid & 63) == 0) sm.c.red[8 + wid] = ssum;
      __syncthreads();
      float S = sm.c.red[8];
#pragma unroll
      for (int i = 1; i < 8; ++i) S += sm.c.red[8 + i];
      const float inv = 1.0f / S;
      sm.c.e[tid] = p0 * inv;
      if (tid < NT - 512) sm.c.e[512 + tid] = p1 * inv;
      if (b == 0) {
        P.out[PRED_SIZE + (size_t)t*NT + tid] = p0 * inv;
        if (tid < NT - 512) P.out[PRED_SIZE + (size_t)t*NT + 512 + tid] = p1 * inv;
      }
      __syncthreads();

      // ctx = attn @ value
      {
        const int kq = tid & 31, tq = tid >> 5;
        const v4f* vb = (const v4f*)(P.val + (size_t)b*NT*NKV);
        v4f a4 = (v4f)0.0f, a42 = (v4f)0.0f;
        int tt = tq;
        for (; tt + 16 < len; tt += 32) {
          a4  += sm.c.e[tt]      * vb[(size_t)tt*32 + kq];
          a42 += sm.c.e[tt + 16] * vb[(size_t)(tt + 16)*32 + kq];
        }
        if (tt < len) a4 += sm.c.e[tt] * vb[(size_t)tt*32 + kq];
        a4 += a42;
        *(v4f*)&sm.c.ctxp[tq][kq*4] = a4;
      }
      __syncthreads();
      if (tid < 128) {
        const int k = tid;
        float c = 0.0f;
#pragma unroll
        for (int r = 0; r < 16; ++r) c += sm.c.ctxp[r][k];
        sm.c.qc[128 + k] = c;
        const ushort_t hi = bf16_rne(c);
        const ushort_t lo = bf16_rne(c - bf16_to_f(hi));
        XEC[((size_t)0*256 + b)*384 + 256 + k] = hi;
        XEC[((size_t)1*256 + b)*384 + 256 + k] = lo;
      }
      __syncthreads();

      // pred
      {
        const int vv = tid >> 4, lg16 = tid & 15;
        if (vv < NV) {
          const v4f* er = (const v4f*)(P.emb + (size_t)vv*NE + lg16*16);
          const v4f* qr = (const v4f*)&sm.c.qc[lg16*16];
          v4f s4 = er[0]*qr[0] + er[1]*qr[1] + er[2]*qr[2] + er[3]*qr[3];
          float p = s4[0] + s4[1] + s4[2] + s4[3];
          p += __shfl_xor(p, 1); p += __shfl_xor(p, 2);
          p += __shfl_xor(p, 4); p += __shfl_xor(p, 8);
          if (lg16 == 0) P.out[((size_t)b*NL + t)*NV + vv] = p + P.ob[vv];
        }
      }

      // x_next emb
      if (tid < 256) {
        const int tok = P.y[(size_t)b*NL + t];
        const float x = P.emb[(size_t)tok*NE + tid];
        const ushort_t hi = bf16_rne(x);
        const ushort_t lo = bf16_rne(x - bf16_to_f(hi));
        XEC[((size_t)0*256 + b)*384 + tid] = hi;
        XEC[((size_t)1*256 + b)*384 + tid] = lo;
      }
    }
    gridbar(bar, G);
  }

  // diagnostic: if the barrier ever broke, make it unmistakable in absmax
  if (bid == 0 && tid == 0) {
    if (__hip_atomic_load(&bar[2], __ATOMIC_RELAXED, __HIP_MEMORY_SCOPE_SYSTEM))
      P.out[0] = 1.0e9f;
  }
}

extern "C" void kernel_launch(void* const* d_in, const int* in_sizes, int n_in,
                              void* d_out, int out_size, void* d_ws, size_t ws_size,
                              hipStream_t stream) {
  (void)in_sizes; (void)n_in; (void)out_size; (void)ws_size;
  DecParams P;
  P.key  = (const float*)d_in[0];
  P.val  = (const float*)d_in[1];
  P.elen = (const int*)d_in[2];
  P.y    = (const int*)d_in[3];
  P.emb  = (const float*)d_in[4];
  P.wi1  = (const float*)d_in[5];
  P.wh1  = (const float*)d_in[6];
  P.bi1  = (const float*)d_in[7];
  P.bh1  = (const float*)d_in[8];
  P.wi2  = (const float*)d_in[9];
  P.wh2  = (const float*)d_in[10];
  P.bi2  = (const float*)d_in[11];
  P.bh2  = (const float*)d_in[12];
  P.ob   = (const float*)d_in[13];
  P.out  = (float*)d_out;
  P.ws   = (float*)d_ws;

  // adaptive co-resident block count (host-side, capture-safe)
  int perCU = 0;
  hipOccupancyMaxActiveBlocksPerMultiprocessor(&perCU, (const void*)k_persist, 512, 0);
  hipDeviceProp_t prop;
  int dev = 0;
  hipGetDevice(&dev);
  hipGetDeviceProperties(&prop, dev);
  int G = perCU * prop.multiProcessorCount;
  if (G > NB) G = NB;
  if (G < 1)  G = 1;

  hipLaunchKernelGGL(k_init,    dim3(2433), dim3(256), 0, stream, P);
  hipLaunchKernelGGL(k_initX,   dim3(256),  dim3(256), 0, stream, P);
  hipLaunchKernelGGL(k_initW,   dim3(2048), dim3(256), 0, stream, P);
  hipLaunchKernelGGL(k_initW2,  dim3(512),  dim3(256), 0, stream, P);
  hipLaunchKernelGGL(k_persist, dim3(G),    dim3(512), 0, stream, P, G);
}

// Round 11
// 24800.430 us; speedup vs baseline: 2.1722x; 2.1722x over previous
//
#include <hip/hip_runtime.h>
#include <cstddef>

// Problem constants
#define NV   30
#define NDH  512
#define NE   256
#define NKV  128
#define NB   256
#define NT   800
#define NL   300
#define NKX  896   // E + KV + DH

#define PRED_SIZE (NB*NL*NV)   // predictions; attn_plot (NL*NT) follows

typedef float v4f __attribute__((ext_vector_type(4)));
typedef short bf16x8 __attribute__((ext_vector_type(8)));
typedef unsigned int v4u __attribute__((ext_vector_type(4)));
typedef unsigned short ushort_t;

// ---- workspace float offsets ----
#define OFF_C1   0                      // C1[512][256]                     (131072 f)
#define OFF_C2   131072                 // C2[128][256]  ([j2][b])          (32768 f)
#define OFF_H2F  163840                 // H2f[256][128] ([b][j2]) fp32     (32768 f)
#define OFF_XEC  196608                 // XEC ushort[2 pl][256 b][384]     (98304 f)
#define OFF_XH1  294912                 // XH1 ushort[2 par][2 pl][256][512](262144 f)
#define OFF_XH2  557056                 // XH2 ushort[2 par][2 pl][256][128](65536 f)
#define OFF_BAR  622592                 // barrier: cnt, gen, broken        (256 f pad)
#define OFF_WF   622848                 // Wf  ushort[2][128][28][64][8]    (1835008 f)
#define OFF_WF2  2457856                // Wf2 ushort[2][32][20][64][8]     (327680 f)
#define OFF_BS1  2785536                // bsum1[2048]
#define OFF_BS2  2787584                // bsum2[512]
// end 2788096 floats = 11.2 MB

#define WF_PL   ((size_t)128*28*64*8)
#define WF2_PL  ((size_t)32*20*64*8)

struct DecParams {
  const float* key; const float* val; const int* elen; const int* y;
  const float* emb;
  const float* wi1; const float* wh1; const float* bi1; const float* bh1;
  const float* wi2; const float* wh2; const float* bi2; const float* bh2;
  const float* ob;
  float* out; float* ws;
};

__device__ __forceinline__ float sigm(float x)  { return 1.0f/(1.0f + __expf(-x)); }
__device__ __forceinline__ float tanh_f(float x){ return 1.0f - 2.0f/(__expf(2.0f*x)+1.0f); }

__device__ __forceinline__ ushort_t bf16_rne(float x){
  union { float f; unsigned u; } v; v.f = x;
  unsigned r = v.u + 0x7FFFu + ((v.u >> 16) & 1u);
  return (ushort_t)(r >> 16);
}
__device__ __forceinline__ float bf16_to_f(ushort_t h){
  union { float f; unsigned u; } v; v.u = ((unsigned)h) << 16;
  return v.f;
}

// ---- L3-coherent (bypass L1/L2) access helpers: sc0 sc1 ----
__device__ __forceinline__ void sys_load2_b128(const ushort_t* p0, const ushort_t* p1,
                                               v4u& a, v4u& b){
  asm volatile("global_load_dwordx4 %0, %2, off sc0 sc1\n\t"
               "global_load_dwordx4 %1, %3, off sc0 sc1\n\t"
               "s_waitcnt vmcnt(0)"
               : "=&v"(a), "=&v"(b)
               : "v"(p0), "v"(p1)
               : "memory");
}
__device__ __forceinline__ void sys_store_short(ushort_t* p, ushort_t v){
  unsigned vv = v;
  asm volatile("global_store_short %0, %1, off sc0 sc1" :: "v"(p), "v"(vv) : "memory");
}
__device__ __forceinline__ void sys_store_dword(float* p, float v){
  asm volatile("global_store_dword %0, %1, off sc0 sc1" :: "v"(p), "v"(v) : "memory");
}
__device__ __forceinline__ float sys_load_dword(const float* p){
  float r;
  asm volatile("global_load_dword %0, %1, off sc0 sc1\n\ts_waitcnt vmcnt(0)"
               : "=v"(r) : "v"(p) : "memory");
  return r;
}
__device__ __forceinline__ int sys_load_int(const int* p){
  int r;
  asm volatile("global_load_dword %0, %1, off sc0 sc1\n\ts_waitcnt vmcnt(0)"
               : "=v"(r) : "v"(p) : "memory");
  return r;
}

// ---- grid barrier: cumulative count; RMW at coherence point; polls via sc0sc1 loads ----
// Release: every wave drains vmcnt (sc0sc1 stores ack'd at L3) before s_barrier.
// Acquire: all cross-block state is read with sc0sc1 loads (never stale L1/L2).
// HARD BOUND: spin cap 8192 iters (~3-5 ms); first timeout sets broken; all later
// barriers pre-check broken (1 load) and exit instantly. Total worst case <10 ms of
// spinning for the whole kernel — cannot wedge the GPU.
__device__ __forceinline__ void gridbar(int* bar, int G, int bnum)
{
  asm volatile("s_waitcnt vmcnt(0)" ::: "memory");
  __syncthreads();
  if (threadIdx.x == 0) {
    const int v = __hip_atomic_fetch_add(&bar[0], 1, __ATOMIC_RELAXED, __HIP_MEMORY_SCOPE_SYSTEM);
    if (v == bnum * G - 1) {
      __hip_atomic_store(&bar[1], bnum, __ATOMIC_RELAXED, __HIP_MEMORY_SCOPE_SYSTEM);
    } else if (sys_load_int(&bar[2]) == 0) {      // skip spin entirely if already broken
      int spins = 0;
      while (sys_load_int(&bar[1]) < bnum) {
        __builtin_amdgcn_s_sleep(8);
        if (++spins > 8192) {                     // ~3-5 ms: flag broken, bail
          __hip_atomic_store(&bar[2], 1, __ATOMIC_RELAXED, __HIP_MEMORY_SCOPE_SYSTEM);
          break;
        }
      }
    }
  }
  __syncthreads();
}

// ---------------- init: zero state + barrier region ----------------
__global__ void __launch_bounds__(256)
k_init(DecParams P)
{
  P.ws[blockIdx.x * 256 + threadIdx.x] = 0.0f;   // grid 2433 -> floats [0, 622848)
}

// ---------------- initX: XEC ctx rows <- value[:,0,:] ----------------
__global__ void __launch_bounds__(256)
k_initX(DecParams P)
{
  const int b = blockIdx.x, tid = threadIdx.x;
  if (tid < 128) {
    ushort_t* xec = (ushort_t*)(P.ws + OFF_XEC);
    const float v = P.val[(size_t)b*NT*NKV + tid];
    const ushort_t hi = bf16_rne(v);
    const ushort_t lo = bf16_rne(v - bf16_to_f(hi));
    xec[((size_t)0*256 + b)*384 + 256 + tid] = hi;
    xec[((size_t)1*256 + b)*384 + 256 + tid] = lo;
  }
}

// ---------------- initW: W1 -> split-bf16 fragment-linear Wf; bsum1 ----------------
__global__ void __launch_bounds__(256)
k_initW(DecParams P)
{
  const int r = blockIdx.x;            // 0..2047
  const int tid = threadIdx.x;
  ushort_t* wf = (ushort_t*)(P.ws + OFF_WF);
  const int rt = r >> 4;
#pragma unroll
  for (int i = 0; i < 4; ++i) {
    const int k = i*256 + tid;
    if (k < NKX) {
      const float w = (k < 384) ? P.wi1[(size_t)r*384 + k]
                                : P.wh1[(size_t)r*512 + (k - 384)];
      const ushort_t hi = bf16_rne(w);
      const ushort_t lo = bf16_rne(w - bf16_to_f(hi));
      const int kc = k >> 5;
      const int lane = (r & 15) | (((k >> 3) & 3) << 4);
      const int e = k & 7;
      const size_t base = ((((size_t)rt)*28 + kc)*64 + lane)*8 + e;
      wf[base] = hi;
      wf[WF_PL + base] = lo;
    }
  }
  if (tid == 0) P.ws[OFF_BS1 + r] = P.bi1[r] + P.bh1[r];
}

// ---------------- initW2 ----------------
__global__ void __launch_bounds__(256)
k_initW2(DecParams P)
{
  const int r = blockIdx.x;            // 0..511
  const int tid = threadIdx.x;
  ushort_t* wf = (ushort_t*)(P.ws + OFF_WF2);
  const int rt = r >> 4;
#pragma unroll
  for (int i = 0; i < 3; ++i) {
    const int k = i*256 + tid;
    if (k < 640) {
      const float w = (k < 512) ? P.wi2[(size_t)r*512 + k]
                                : P.wh2[(size_t)r*128 + (k - 512)];
      const ushort_t hi = bf16_rne(w);
      const ushort_t lo = bf16_rne(w - bf16_to_f(hi));
      const int kc = k >> 5;
      const int lane = (r & 15) | (((k >> 3) & 3) << 4);
      const int e = k & 7;
      const size_t base = ((((size_t)rt)*20 + kc)*64 + lane)*8 + e;
      wf[base] = hi;
      wf[WF2_PL + base] = lo;
    }
  }
  if (tid == 0) P.ws[OFF_BS2 + r] = P.bi2[r] + P.bh2[r];
}

// ---------------- persistent kernel ----------------
// xs: [plane][row b][128 k] with XOR swizzle on the 16B unit: u' = u ^ (row&7)
// -> 2-way (free) ds_read_b128 / ds_write_b128
union SMem {
  struct { ushort_t xs[2][32][128]; float gbuf[4][16][33]; } ab;   // 24.6 KB
  struct { float e[NT]; float qc[256]; float red[16]; float ctxp[16][132]; } c; // 12.7 KB
};

__global__ void __launch_bounds__(512)
k_persist(DecParams P, int G)
{
  __shared__ SMem sm;
  const int tid = threadIdx.x;
  const int bid = blockIdx.x;
  const int w = tid >> 6, lane = tid & 63;
  const int lr = lane & 15, g16 = lane >> 4;
  const int srow = tid >> 4, u = tid & 15;
  const int su_w = (u ^ (srow & 7)) * 8;       // swizzled staging write offset (ushorts)

  float* ws = P.ws;
  int* bar = (int*)(ws + OFF_BAR);
  const ushort_t* Wf  = (const ushort_t*)(ws + OFF_WF);
  const ushort_t* Wf2 = (const ushort_t*)(ws + OFF_WF2);
  ushort_t* XEC = (ushort_t*)(ws + OFF_XEC);
  ushort_t* XH1 = (ushort_t*)(ws + OFF_XH1);
  ushort_t* XH2 = (ushort_t*)(ws + OFF_XH2);
  float* C1  = ws + OFF_C1;
  float* C2  = ws + OFF_C2;
  float* H2f = ws + OFF_H2F;
  const float* BS1 = ws + OFF_BS1;
  const float* BS2 = ws + OFF_BS2;

  int bnum = 0;

#pragma unroll 1
  for (int t = 0; t < NL; ++t) {
    const int cur = t & 1, nxt = (t + 1) & 1;

    // ================= Phase A: LSTM1 (256 tiles) =================
#pragma unroll 1
    for (int tileA = bid; tileA < 256; tileA += G) {
      const int mt = tileA & 31, nt = tileA >> 5;
      const int b0 = nt * 32, j0 = mt * 16;
      const int g = w >> 1, ct = w & 1;
      const int rt16 = g*32 + mt;
      v4f acc = (v4f)0.0f;

#pragma unroll 1
      for (int p = 0; p < 7; ++p) {
        __syncthreads();
        {
          const ushort_t *s0, *s1;
          if (p < 3) {
            s0 = XEC + ((size_t)(0*256 + b0 + srow))*384 + p*128 + u*8;
            s1 = XEC + ((size_t)(1*256 + b0 + srow))*384 + p*128 + u*8;
          } else {
            s0 = XH1 + (((size_t)cur*2 + 0)*256 + b0 + srow)*512 + (p-3)*128 + u*8;
            s1 = XH1 + (((size_t)cur*2 + 1)*256 + b0 + srow)*512 + (p-3)*128 + u*8;
          }
          v4u d0, d1;
          sys_load2_b128(s0, s1, d0, d1);
          *(v4u*)&sm.ab.xs[0][srow][su_w] = d0;
          *(v4u*)&sm.ab.xs[1][srow][su_w] = d1;
        }
        __syncthreads();
#pragma unroll
        for (int kc2 = 0; kc2 < 4; ++kc2) {
          const int kcg = p*4 + kc2;
          bf16x8 ah = *(const bf16x8*)(Wf + (((size_t)rt16*28 + kcg)*64 + lane)*8);
          bf16x8 al = *(const bf16x8*)(Wf + WF_PL + (((size_t)rt16*28 + kcg)*64 + lane)*8);
          const int su_r = ((kc2*4 + g16) ^ (lr & 7)) * 8;
          bf16x8 bh = *(const bf16x8*)&sm.ab.xs[0][ct*16 + lr][su_r];
          bf16x8 bl = *(const bf16x8*)&sm.ab.xs[1][ct*16 + lr][su_r];
          acc = __builtin_amdgcn_mfma_f32_16x16x32_bf16(ah, bh, acc, 0, 0, 0);
          acc = __builtin_amdgcn_mfma_f32_16x16x32_bf16(ah, bl, acc, 0, 0, 0);
          acc = __builtin_amdgcn_mfma_f32_16x16x32_bf16(al, bh, acc, 0, 0, 0);
        }
      }
      __syncthreads();
      {
        const int rg = g16 * 4;
#pragma unroll
        for (int j = 0; j < 4; ++j) sm.ab.gbuf[g][rg + j][ct*16 + lr] = acc[j];
      }
      __syncthreads();
      {
        const int jj = tid >> 5, bq = tid & 31;
        const int jg = j0 + jj, b = b0 + bq;
        const float iv = sigm (sm.ab.gbuf[0][jj][bq] + BS1[       jg]);
        const float fv = sigm (sm.ab.gbuf[1][jj][bq] + BS1[ 512 + jg]);
        const float gv = tanh_f(sm.ab.gbuf[2][jj][bq] + BS1[1024 + jg]);
        const float ov = sigm (sm.ab.gbuf[3][jj][bq] + BS1[1536 + jg]);
        const float cn = fv * C1[(size_t)jg*256 + b] + iv * gv;
        C1[(size_t)jg*256 + b] = cn;
        const float h = ov * tanh_f(cn);
        const ushort_t hi = bf16_rne(h);
        const ushort_t lo = bf16_rne(h - bf16_to_f(hi));
        sys_store_short(XH1 + (((size_t)nxt*2 + 0)*256 + b)*512 + jg, hi);
        sys_store_short(XH1 + (((size_t)nxt*2 + 1)*256 + b)*512 + jg, lo);
      }
    }
    bnum++; gridbar(bar, G, bnum);

    // ================= Phase B: LSTM2 (64 tiles) =================
#pragma unroll 1
    for (int tileB = bid; tileB < 64; tileB += G) {
      const int mt = tileB & 7, nt = tileB >> 3;
      const int b0 = nt * 32, j0 = mt * 16;
      const int g = w >> 1, ct = w & 1;
      const int rt16 = g*8 + mt;
      v4f acc = (v4f)0.0f;

#pragma unroll 1
      for (int p = 0; p < 5; ++p) {
        __syncthreads();
        {
          const ushort_t *s0, *s1;
          if (p < 4) {
            s0 = XH1 + (((size_t)nxt*2 + 0)*256 + b0 + srow)*512 + p*128 + u*8;
            s1 = XH1 + (((size_t)nxt*2 + 1)*256 + b0 + srow)*512 + p*128 + u*8;
          } else {
            s0 = XH2 + (((size_t)cur*2 + 0)*256 + b0 + srow)*128 + u*8;
            s1 = XH2 + (((size_t)cur*2 + 1)*256 + b0 + srow)*128 + u*8;
          }
          v4u d0, d1;
          sys_load2_b128(s0, s1, d0, d1);
          *(v4u*)&sm.ab.xs[0][srow][su_w] = d0;
          *(v4u*)&sm.ab.xs[1][srow][su_w] = d1;
        }
        __syncthreads();
#pragma unroll
        for (int kc2 = 0; kc2 < 4; ++kc2) {
          const int kcg = p*4 + kc2;
          bf16x8 ah = *(const bf16x8*)(Wf2 + (((size_t)rt16*20 + kcg)*64 + lane)*8);
          bf16x8 al = *(const bf16x8*)(Wf2 + WF2_PL + (((size_t)rt16*20 + kcg)*64 + lane)*8);
          const int su_r = ((kc2*4 + g16) ^ (lr & 7)) * 8;
          bf16x8 bh = *(const bf16x8*)&sm.ab.xs[0][ct*16 + lr][su_r];
          bf16x8 bl = *(const bf16x8*)&sm.ab.xs[1][ct*16 + lr][su_r];
          acc = __builtin_amdgcn_mfma_f32_16x16x32_bf16(ah, bh, acc, 0, 0, 0);
          acc = __builtin_amdgcn_mfma_f32_16x16x32_bf16(ah, bl, acc, 0, 0, 0);
          acc = __builtin_amdgcn_mfma_f32_16x16x32_bf16(al, bh, acc, 0, 0, 0);
        }
      }
      __syncthreads();
      {
        const int rg = g16 * 4;
#pragma unroll
        for (int j = 0; j < 4; ++j) sm.ab.gbuf[g][rg + j][ct*16 + lr] = acc[j];
      }
      __syncthreads();
      {
        const int jj = tid >> 5, bq = tid & 31;
        const int j2 = j0 + jj, b = b0 + bq;
        const float iv = sigm (sm.ab.gbuf[0][jj][bq] + BS2[      j2]);
        const float fv = sigm (sm.ab.gbuf[1][jj][bq] + BS2[128 + j2]);
        const float gv = tanh_f(sm.ab.gbuf[2][jj][bq] + BS2[256 + j2]);
        const float ov = sigm (sm.ab.gbuf[3][jj][bq] + BS2[384 + j2]);
        const float cn = fv * C2[(size_t)j2*256 + b] + iv * gv;
        C2[(size_t)j2*256 + b] = cn;
        const float h = ov * tanh_f(cn);
        sys_store_dword(H2f + (size_t)b*128 + j2, h);
        const ushort_t hi = bf16_rne(h);
        const ushort_t lo = bf16_rne(h - bf16_to_f(hi));
        sys_store_short(XH2 + (((size_t)nxt*2 + 0)*256 + b)*128 + j2, hi);
        sys_store_short(XH2 + (((size_t)nxt*2 + 1)*256 + b)*128 + j2, lo);
      }
    }
    bnum++; gridbar(bar, G, bnum);

    // ================= Phase C: attention + pred + x_next (256 tiles) =================
#pragma unroll 1
    for (int b = bid; b < NB; b += G) {
      __syncthreads();   // protect sm.c reuse across b-tiles
      const int len = P.elen[b];

      if (tid < 128) sm.c.qc[tid] = sys_load_dword(H2f + (size_t)b*128 + tid);
      __syncthreads();

      // energy (key reads stay cached — no flushes)
      const int lg = tid & 15, grp = tid >> 4;
      const v4f qa = *(const v4f*)&sm.c.qc[lg*8];
      const v4f qb = *(const v4f*)&sm.c.qc[lg*8 + 4];
      const v4f* kb = (const v4f*)(P.key + (size_t)b*NT*NKV);
#pragma unroll 1
      for (int s = 0; s < 13; ++s) {
        const int ta = s*64 + grp, tb = ta + 32;
        float pa = 0.0f, pb = 0.0f;
        if (ta < len) {
          v4f k0 = kb[(size_t)ta*32 + lg*2], k1 = kb[(size_t)ta*32 + lg*2 + 1];
          v4f d = k0*qa + k1*qb; pa = d[0]+d[1]+d[2]+d[3];
        }
        if (tb < len) {
          v4f k0 = kb[(size_t)tb*32 + lg*2], k1 = kb[(size_t)tb*32 + lg*2 + 1];
          v4f d = k0*qa + k1*qb; pb = d[0]+d[1]+d[2]+d[3];
        }
        pa += __shfl_xor(pa, 1); pb += __shfl_xor(pb, 1);
        pa += __shfl_xor(pa, 2); pb += __shfl_xor(pb, 2);
        pa += __shfl_xor(pa, 4); pb += __shfl_xor(pb, 4);
        pa += __shfl_xor(pa, 8); pb += __shfl_xor(pb, 8);
        if (lg == 0) {
          if (ta < len) sm.c.e[ta] = pa;
          if (tb < len) sm.c.e[tb] = pb;
        }
      }
      for (int tt = len + tid; tt < NT; tt += 512) sm.c.e[tt] = -1e9f;
      __syncthreads();

      // softmax
      const int wid = tid >> 6;
      const float x0 = sm.c.e[tid];
      const float x1 = (tid < NT - 512) ? sm.c.e[512 + tid] : -3.0e38f;
      float m = fmaxf(x0, x1);
      m = fmaxf(m, __shfl_xor(m, 1));  m = fmaxf(m, __shfl_xor(m, 2));
      m = fmaxf(m, __shfl_xor(m, 4));  m = fmaxf(m, __shfl_xor(m, 8));
      m = fmaxf(m, __shfl_xor(m, 16)); m = fmaxf(m, __shfl_xor(m, 32));
      if ((tid & 63) == 0) sm.c.red[wid] = m;
      __syncthreads();
      m = sm.c.red[0];
#pragma unroll
      for (int i = 1; i < 8; ++i) m = fmaxf(m, sm.c.red[i]);
      const float p0 = __expf(x0 - m);
      const float p1 = (tid < NT - 512) ? __expf(x1 - m) : 0.0f;
      float ssum = p0 + p1;
      ssum += __shfl_xor(ssum, 1);  ssum += __shfl_xor(ssum, 2);  ssum += __shfl_xor(ssum, 4);
      ssum += __shfl_xor(ssum, 8);  ssum += __shfl_xor(ssum, 16); ssum += __shfl_xor(ssum, 32);
      __syncthreads();
      if ((tid & 63) == 0) sm.c.red[8 + wid] = ssum;
      __syncthreads();
      float S = sm.c.red[8];
#pragma unroll
      for (int i = 1; i < 8; ++i) S += sm.c.red[8 + i];
      const float inv = 1.0f / S;
      sm.c.e[tid] = p0 * inv;
      if (tid < NT - 512) sm.c.e[512 + tid] = p1 * inv;
      if (b == 0) {
        P.out[PRED_SIZE + (size_t)t*NT + tid] = p0 * inv;
        if (tid < NT - 512) P.out[PRED_SIZE + (size_t)t*NT + 512 + tid] = p1 * inv;
      }
      __syncthreads();

      // ctx = attn @ value
      {
        const int kq = tid & 31, tq = tid >> 5;
        const v4f* vb = (const v4f*)(P.val + (size_t)b*NT*NKV);
        v4f a4 = (v4f)0.0f, a42 = (v4f)0.0f;
        int tt = tq;
        for (; tt + 16 < len; tt += 32) {
          a4  += sm.c.e[tt]      * vb[(size_t)tt*32 + kq];
          a42 += sm.c.e[tt + 16] * vb[(size_t)(tt + 16)*32 + kq];
        }
        if (tt < len) a4 += sm.c.e[tt] * vb[(size_t)tt*32 + kq];
        a4 += a42;
        *(v4f*)&sm.c.ctxp[tq][kq*4] = a4;
      }
      __syncthreads();
      if (tid < 128) {
        const int k = tid;
        float c = 0.0f;
#pragma unroll
        for (int r = 0; r < 16; ++r) c += sm.c.ctxp[r][k];
        sm.c.qc[128 + k] = c;
        const ushort_t hi = bf16_rne(c);
        const ushort_t lo = bf16_rne(c - bf16_to_f(hi));
        sys_store_short(XEC + ((size_t)0*256 + b)*384 + 256 + k, hi);
        sys_store_short(XEC + ((size_t)1*256 + b)*384 + 256 + k, lo);
      }
      __syncthreads();

      // pred = [h2|ctx] @ emb^T + bias
      {
        const int vv = tid >> 4, lg16 = tid & 15;
        if (vv < NV) {
          const v4f* er = (const v4f*)(P.emb + (size_t)vv*NE + lg16*16);
          const v4f* qr = (const v4f*)&sm.c.qc[lg16*16];
          v4f s4 = er[0]*qr[0] + er[1]*qr[1] + er[2]*qr[2] + er[3]*qr[3];
          float p = s4[0] + s4[1] + s4[2] + s4[3];
          p += __shfl_xor(p, 1); p += __shfl_xor(p, 2);
          p += __shfl_xor(p, 4); p += __shfl_xor(p, 8);
          if (lg16 == 0) P.out[((size_t)b*NL + t)*NV + vv] = p + P.ob[vv];
        }
      }

      // x_next: emb(y[b][t])
      if (tid < 256) {
        const int tok = P.y[(size_t)b*NL + t];
        const float x = P.emb[(size_t)tok*NE + tid];
        const ushort_t hi = bf16_rne(x);
        const ushort_t lo = bf16_rne(x - bf16_to_f(hi));
        sys_store_short(XEC + ((size_t)0*256 + b)*384 + tid, hi);
        sys_store_short(XEC + ((size_t)1*256 + b)*384 + tid, lo);
      }
    }
    bnum++; gridbar(bar, G, bnum);
  }

  // diagnostic: if the barrier ever broke, make it unmistakable in absmax
  if (bid == 0 && tid == 0) {
    if (sys_load_int(&bar[2]) != 0)
      P.out[0] = 1.0e9f;
  }
}

extern "C" void kernel_launch(void* const* d_in, const int* in_sizes, int n_in,
                              void* d_out, int out_size, void* d_ws, size_t ws_size,
                              hipStream_t stream) {
  (void)in_sizes; (void)n_in; (void)out_size; (void)ws_size;
  DecParams P;
  P.key  = (const float*)d_in[0];
  P.val  = (const float*)d_in[1];
  P.elen = (const int*)d_in[2];
  P.y    = (const int*)d_in[3];
  P.emb  = (const float*)d_in[4];
  P.wi1  = (const float*)d_in[5];
  P.wh1  = (const float*)d_in[6];
  P.bi1  = (const float*)d_in[7];
  P.bh1  = (const float*)d_in[8];
  P.wi2  = (const float*)d_in[9];
  P.wh2  = (const float*)d_in[10];
  P.bi2  = (const float*)d_in[11];
  P.bh2  = (const float*)d_in[12];
  P.ob   = (const float*)d_in[13];
  P.out  = (float*)d_out;
  P.ws   = (float*)d_ws;

  // adaptive co-resident block count (host-side, capture-safe)
  int perCU = 0;
  hipOccupancyMaxActiveBlocksPerMultiprocessor(&perCU, (const void*)k_persist, 512, 0);
  hipDeviceProp_t prop;
  int dev = 0;
  hipGetDevice(&dev);
  hipGetDeviceProperties(&prop, dev);
  int G = perCU * prop.multiProcessorCount;
  if (G > NB) G = NB;
  if (G < 1)  G = 1;

  hipLaunchKernelGGL(k_init,    dim3(2433), dim3(256), 0, stream, P);
  hipLaunchKernelGGL(k_initX,   dim3(256),  dim3(256), 0, stream, P);
  hipLaunchKernelGGL(k_initW,   dim3(2048), dim3(256), 0, stream, P);
  hipLaunchKernelGGL(k_initW2,  dim3(512),  dim3(256), 0, stream, P);
  hipLaunchKernelGGL(k_persist, dim3(G),    dim3(512), 0, stream, P, G);
}